// Round 11
// baseline (540.367 us; speedup 1.0000x reference)
//
#include <hip/hip_runtime.h>
#include <math.h>

#define NEG_SLOPE 0.2f
#define EPSF 1e-16f

constexpr int FIN = 128;
constexpr int H1  = 4;
constexpr int C   = 64;
constexpr int HC  = 256;   // H1 * C

typedef __attribute__((ext_vector_type(8))) short bf16x8;
typedef __attribute__((ext_vector_type(4))) float f32x4;

__device__ inline float wredsum(float v) {
#pragma unroll
    for (int off = 32; off; off >>= 1) v += __shfl_down(v, off);
    return v;
}
__device__ inline float wredmax(float v) {
#pragma unroll
    for (int off = 32; off; off >>= 1) v = fmaxf(v, __shfl_down(v, off));
    return v;
}
__device__ inline float4 wredmax4(float4 v) {
#pragma unroll
    for (int off = 32; off; off >>= 1) {
        v.x = fmaxf(v.x, __shfl_down(v.x, off));
        v.y = fmaxf(v.y, __shfl_down(v.y, off));
        v.z = fmaxf(v.z, __shfl_down(v.z, off));
        v.w = fmaxf(v.w, __shfl_down(v.w, off));
    }
    return v;
}
__device__ inline float4 wredsum4(float4 v) {
#pragma unroll
    for (int off = 32; off; off >>= 1) {
        v.x += __shfl_down(v.x, off);
        v.y += __shfl_down(v.y, off);
        v.z += __shfl_down(v.z, off);
        v.w += __shfl_down(v.w, off);
    }
    return v;
}
__device__ inline float4 bcast4(float4 v) {
    v.x = __shfl(v.x, 0); v.y = __shfl(v.y, 0);
    v.z = __shfl(v.z, 0); v.w = __shfl(v.w, 0);
    return v;
}
__device__ inline float comp4(float4 v, int i) {
    return i == 0 ? v.x : (i == 1 ? v.y : (i == 2 ? v.z : v.w));
}
__device__ inline unsigned short f2bf(float f) {   // RNE
    unsigned u = __float_as_uint(f);
    return (unsigned short)((u + 0x7fffu + ((u >> 16) & 1u)) >> 16);
}

// ---------- merged histogram + edge_attr sum ----------
__global__ void k_hist_ea(const int* __restrict__ ei, const float* __restrict__ eattr,
                          int* __restrict__ deg, float* __restrict__ scal, int E, int Etot) {
    int e = blockIdx.x * blockDim.x + threadIdx.x;
    float v = 0.0f;
    if (e < Etot) {
        int d = (e < E) ? ei[E + e] : e - E;
        atomicAdd(&deg[d], 1);
        if (e < E) v = eattr[e];
    }
    v = wredsum(v);
    __shared__ float sm[4];
    if ((threadIdx.x & 63) == 0) sm[threadIdx.x >> 6] = v;
    __syncthreads();
    if (threadIdx.x == 0) atomicAdd(scal, sm[0] + sm[1] + sm[2] + sm[3]);
}

// scal[1]=ea_mean, scal[2]=we2dot, scal[4..7]=we1dot[h]
__global__ void k_prep(const float* __restrict__ We1, const float* __restrict__ ae1,
                       const float* __restrict__ We2, const float* __restrict__ ae2,
                       float* __restrict__ scal, float inv_E) {
    int t = threadIdx.x;
    float p = We1[t] * ae1[t];
    p = wredsum(p);
    if ((t & 63) == 0) scal[4 + (t >> 6)] = p;
    if (t < 64) {
        float q = We2[t] * ae2[t];
        q = wredsum(q);
        if (t == 0) scal[2] = q;
    }
    if (t == 0) scal[1] = scal[0] * inv_E;
}

// ---------- vsd[which][h][k] = sum_c W1[k, h*64+c] * att[h][c] ----------
__global__ void k_prepvec(const float* __restrict__ W1, const float* __restrict__ as1,
                          const float* __restrict__ ad1, float* __restrict__ vsd) {
    int idx = blockIdx.x * 256 + threadIdx.x;   // 0..1023
    int which = idx >> 9, h = (idx >> 7) & 3, k = idx & 127;
    const float* att = which ? ad1 : as1;
    float s = 0.0f;
#pragma unroll 8
    for (int c = 0; c < 64; ++c) s += W1[k * HC + h * 64 + c] * att[h * 64 + c];
    vsd[idx] = s;
}

// ---------- convert W1/W2 to bf16 MFMA fragment order ----------
__global__ void k_convw(const float* __restrict__ W1, const float* __restrict__ W2,
                        unsigned short* __restrict__ W1f, unsigned short* __restrict__ W2f) {
    int idx = blockIdx.x * 256 + threadIdx.x;   // 32768 total
    {
        int j = idx & 7, l = (idx >> 3) & 63, t = (idx >> 9) & 3, q = idx >> 11;
        int k = t * 32 + (l >> 4) * 8 + j;
        int n = 16 * q + (l & 15);
        W1f[idx] = f2bf(W1[k * HC + n]);
    }
    if (idx < 16384) {
        int j = idx & 7, l = (idx >> 3) & 63, t = (idx >> 9) & 7, g = idx >> 12;
        int k = t * 32 + (l >> 4) * 8 + j;
        int c = 16 * g + (l & 15);
        W2f[idx] = f2bf(W2[k * C + c]);
    }
}

// ---------- CSR scans + scatter ----------
__global__ void k_scan1(const int* __restrict__ deg, int* __restrict__ rowstart,
                        int* __restrict__ bsums, int N) {
    __shared__ int sm[256];
    int i = blockIdx.x * 256 + threadIdx.x;
    int v = (i < N) ? deg[i] : 0;
    sm[threadIdx.x] = v;
    __syncthreads();
    for (int off = 1; off < 256; off <<= 1) {
        int t = (threadIdx.x >= off) ? sm[threadIdx.x - off] : 0;
        __syncthreads();
        sm[threadIdx.x] += t;
        __syncthreads();
    }
    if (i < N) rowstart[i] = sm[threadIdx.x] - v;   // exclusive
    if (threadIdx.x == 255) bsums[blockIdx.x] = sm[255];
}

__global__ void k_scan2(int* __restrict__ bsums, int nb) {
    __shared__ int sm[256];
    int v = (threadIdx.x < nb) ? bsums[threadIdx.x] : 0;
    sm[threadIdx.x] = v;
    __syncthreads();
    for (int off = 1; off < 256; off <<= 1) {
        int t = (threadIdx.x >= off) ? sm[threadIdx.x - off] : 0;
        __syncthreads();
        sm[threadIdx.x] += t;
        __syncthreads();
    }
    if (threadIdx.x < nb) bsums[threadIdx.x] = sm[threadIdx.x] - v;   // exclusive
}

__global__ void k_scan3(int* __restrict__ rowstart, const int* __restrict__ bsums, int N) {
    int i = blockIdx.x * 256 + threadIdx.x;
    if (i < N) rowstart[i] += bsums[blockIdx.x];
}

__global__ void k_scatter(const int* __restrict__ ei, const float* __restrict__ eattr,
                          const float* __restrict__ scal, const int* __restrict__ rowstart,
                          int* __restrict__ cursor, int2* __restrict__ csr, int E, int Etot) {
    int e = blockIdx.x * blockDim.x + threadIdx.x;
    if (e >= Etot) return;
    int s, d; float ea;
    if (e < E) { s = ei[e]; d = ei[E + e]; ea = eattr[e]; }
    else       { s = e - E; d = s;          ea = scal[1]; }
    int pos = atomicAdd(&cursor[d], 1);
    csr[rowstart[d] + pos] = make_int2(s, __float_as_int(ea));
}

// ---------- convert x -> bf16, compute a_src1/a_dst1 via precomputed vectors ----------
// one wave per node; lane l covers channels 2l, 2l+1
__global__ void k_convx(const float* __restrict__ x, const float* __restrict__ vsd,
                        unsigned int* __restrict__ xb,
                        float* __restrict__ a_src, float* __restrict__ a_dst) {
    int wid = threadIdx.x >> 6, l = threadIdx.x & 63;
    int n = blockIdx.x * 4 + wid;
    float2 xv = ((const float2*)x)[(size_t)n * 64 + l];
    const float2* vs2 = (const float2*)vsd;
    float4 A, B;
    {
        float2 a0 = vs2[l],        a1 = vs2[64 + l];
        float2 a2 = vs2[128 + l],  a3 = vs2[192 + l];
        A.x = xv.x * a0.x + xv.y * a0.y;
        A.y = xv.x * a1.x + xv.y * a1.y;
        A.z = xv.x * a2.x + xv.y * a2.y;
        A.w = xv.x * a3.x + xv.y * a3.y;
        float2 b0 = vs2[256 + l],  b1 = vs2[320 + l];
        float2 b2 = vs2[384 + l],  b3 = vs2[448 + l];
        B.x = xv.x * b0.x + xv.y * b0.y;
        B.y = xv.x * b1.x + xv.y * b1.y;
        B.z = xv.x * b2.x + xv.y * b2.y;
        B.w = xv.x * b3.x + xv.y * b3.y;
    }
    A = wredsum4(A);
    B = wredsum4(B);
    if (l == 0) {
        ((float4*)a_src)[n] = A;
        ((float4*)a_dst)[n] = B;
    }
    xb[(size_t)n * 64 + l] = f2bf(xv.x) | ((unsigned)f2bf(xv.y) << 16);
}

// ---------- layer 1 aggregation in x-space: per-head xagg, bf16 gather 256 B/edge ----------
// one wave per node; half = lane>>5 handles edges jj+half; lane covers channels 4hl..4hl+3
__global__ void k_agg1x(const int* __restrict__ rowstart, const int* __restrict__ deg,
                        const int2* __restrict__ csr,
                        const float* __restrict__ a_src, const float* __restrict__ a_dst,
                        const float* __restrict__ scal, const uint2* __restrict__ xb2,
                        uint2* __restrict__ xaggb2) {
    __shared__ float4 wlds[4][64];
    int wid = threadIdx.x >> 6, lane = threadIdx.x & 63;
    int n = blockIdx.x * 4 + wid;
    int half = lane >> 5, hl = lane & 31;
    int rs = rowstart[n], cnt = deg[n];
    const float4 adv = ((const float4*)a_dst)[n];
    const float4 wh  = *((const float4*)(scal + 4));

    float4 M = make_float4(-INFINITY, -INFINITY, -INFINITY, -INFINITY);
    float4 den = make_float4(0.f, 0.f, 0.f, 0.f);
    float acc[4][4];
#pragma unroll
    for (int h = 0; h < 4; ++h)
#pragma unroll
        for (int c = 0; c < 4; ++c) acc[h][c] = 0.0f;

    for (int base = 0; base < cnt; base += 64) {
        int j = base + lane;
        int sj = 0;
        float4 al = make_float4(-INFINITY, -INFINITY, -INFINITY, -INFINITY);
        if (j < cnt) {
            int2 cv = csr[rs + j];
            sj = cv.x;
            float ea = __int_as_float(cv.y);
            float4 as4 = ((const float4*)a_src)[sj];
            al.x = as4.x + adv.x + ea * wh.x;
            al.y = as4.y + adv.y + ea * wh.y;
            al.z = as4.z + adv.z + ea * wh.z;
            al.w = as4.w + adv.w + ea * wh.w;
            al.x = al.x > 0.f ? al.x : NEG_SLOPE * al.x;
            al.y = al.y > 0.f ? al.y : NEG_SLOPE * al.y;
            al.z = al.z > 0.f ? al.z : NEG_SLOPE * al.z;
            al.w = al.w > 0.f ? al.w : NEG_SLOPE * al.w;
        }
        float4 cm = bcast4(wredmax4(al));
        float4 newM = make_float4(fmaxf(M.x, cm.x), fmaxf(M.y, cm.y),
                                  fmaxf(M.z, cm.z), fmaxf(M.w, cm.w));
        float4 sc = make_float4(__expf(M.x - newM.x), __expf(M.y - newM.y),
                                __expf(M.z - newM.z), __expf(M.w - newM.w));
        den.x *= sc.x; den.y *= sc.y; den.z *= sc.z; den.w *= sc.w;
#pragma unroll
        for (int h = 0; h < 4; ++h) {
            float s = comp4(sc, h);
#pragma unroll
            for (int c = 0; c < 4; ++c) acc[h][c] *= s;
        }
        M = newM;
        float4 w4 = make_float4(__expf(al.x - M.x), __expf(al.y - M.y),
                                __expf(al.z - M.z), __expf(al.w - M.w));
        den.x += w4.x; den.y += w4.y; den.z += w4.z; den.w += w4.w;
        wlds[wid][lane] = w4;
        int m = min(64, cnt - base);
        for (int jj = 0; jj < m; jj += 2) {
            int idx = jj + half;                 // idx <= 63; padded entries have w=0
            float4 we = wlds[wid][idx];
            int s = __shfl(sj, idx);
            uint2 v = xb2[(size_t)s * 32 + hl];
            float c0 = __uint_as_float(v.x << 16);
            float c1 = __uint_as_float(v.x & 0xffff0000u);
            float c2 = __uint_as_float(v.y << 16);
            float c3 = __uint_as_float(v.y & 0xffff0000u);
            acc[0][0] += c0 * we.x; acc[0][1] += c1 * we.x;
            acc[0][2] += c2 * we.x; acc[0][3] += c3 * we.x;
            acc[1][0] += c0 * we.y; acc[1][1] += c1 * we.y;
            acc[1][2] += c2 * we.y; acc[1][3] += c3 * we.y;
            acc[2][0] += c0 * we.z; acc[2][1] += c1 * we.z;
            acc[2][2] += c2 * we.z; acc[2][3] += c3 * we.z;
            acc[3][0] += c0 * we.w; acc[3][1] += c1 * we.w;
            acc[3][2] += c2 * we.w; acc[3][3] += c3 * we.w;
        }
    }
    float4 dt = bcast4(wredsum4(den));
    float4 inv = make_float4(1.0f / (dt.x + EPSF), 1.0f / (dt.y + EPSF),
                             1.0f / (dt.z + EPSF), 1.0f / (dt.w + EPSF));
    // combine edge-halves: lanes l and l^32 both end with the full sum
#pragma unroll
    for (int h = 0; h < 4; ++h)
#pragma unroll
        for (int c = 0; c < 4; ++c) acc[h][c] += __shfl_xor(acc[h][c], 32);
    int h0 = half * 2;
    float iv0 = comp4(inv, h0), iv1 = comp4(inv, h0 + 1);
    uint2 o0, o1;
    o0.x = f2bf(acc[h0][0] * iv0)     | ((unsigned)f2bf(acc[h0][1] * iv0) << 16);
    o0.y = f2bf(acc[h0][2] * iv0)     | ((unsigned)f2bf(acc[h0][3] * iv0) << 16);
    o1.x = f2bf(acc[h0 + 1][0] * iv1) | ((unsigned)f2bf(acc[h0 + 1][1] * iv1) << 16);
    o1.y = f2bf(acc[h0 + 1][2] * iv1) | ((unsigned)f2bf(acc[h0 + 1][3] * iv1) << 16);
    xaggb2[((size_t)n * 4 + h0) * 32 + hl]     = o0;
    xaggb2[((size_t)n * 4 + h0 + 1) * 32 + hl] = o1;
}

// ---------- fused layer-1 GEMM + ELU + layer-2 GEMM (MFMA), out1 never leaves LDS ----------
// 16 nodes/block, 4 waves. Phase1: wave g = head g. Phase2: wave g = col-tile g.
__global__ void k_fused12(const unsigned short* __restrict__ xaggb,
                          const unsigned short* __restrict__ W1f,
                          const float* __restrict__ b1,
                          const unsigned short* __restrict__ W2f,
                          const float* __restrict__ attsrc, const float* __restrict__ attdst,
                          unsigned short* __restrict__ h2b,
                          float* __restrict__ a_src2, float* __restrict__ a_dst2) {
    __shared__ unsigned short ols[16 * 256];   // 8 KB out1 tile, swizzled
    __shared__ unsigned short hs2[16 * 64];    // 2 KB h2 repack
    __shared__ float pls[2][4][16];
    int t = threadIdx.x;
    int n0 = blockIdx.x * 16;
    int g = t >> 6, l = t & 63;
    int coll = l & 15, hi = l >> 4;
    // phase 1: out1 = ELU(xagg[:,g] @ W1[:,64g..] + b1)
    const bf16x8* af = (const bf16x8*)xaggb;
    size_t abase = ((size_t)(n0 + coll) * 4 + g) * 16;
    bf16x8 a[4];
#pragma unroll
    for (int k = 0; k < 4; ++k) a[k] = af[abase + k * 4 + hi];
    const bf16x8* wf1 = (const bf16x8*)W1f;
    f32x4 acc1[4];
#pragma unroll
    for (int ct = 0; ct < 4; ++ct) {
        f32x4 c = {0.f, 0.f, 0.f, 0.f};
#pragma unroll
        for (int k = 0; k < 4; ++k) {
            bf16x8 b = wf1[((g * 4 + ct) * 4 + k) * 64 + l];
            c = __builtin_amdgcn_mfma_f32_16x16x32_bf16(a[k], b, c, 0, 0, 0);
        }
        acc1[ct] = c;
    }
#pragma unroll
    for (int ct = 0; ct < 4; ++ct)
#pragma unroll
        for (int r = 0; r < 4; ++r) {
            int row = hi * 4 + r;
            int col = g * 64 + ct * 16 + coll;
            float v = acc1[ct][r] + b1[col];
            v = v > 0.f ? v : expm1f(v);
            ols[row * 256 + (((col >> 3) ^ (row & 7)) << 3) + (col & 7)] = f2bf(v);
        }
    __syncthreads();
    // phase 2: h2 = out1 @ W2 (K=256, 8 k-steps); wave g = cols 16g..16g+15
    const bf16x8* wf2 = (const bf16x8*)W2f;
    f32x4 acc = {0.f, 0.f, 0.f, 0.f};
#pragma unroll
    for (int k = 0; k < 8; ++k) {
        int ch = (k * 4 + hi) ^ (coll & 7);
        bf16x8 av = *(const bf16x8*)((const char*)ols + coll * 512 + ch * 16);
        bf16x8 bv = wf2[(g * 8 + k) * 64 + l];
        acc = __builtin_amdgcn_mfma_f32_16x16x32_bf16(av, bv, acc, 0, 0, 0);
    }
    float as_ = attsrc[g * 16 + coll];
    float ad_ = attdst[g * 16 + coll];
    float ps[4], pd[4];
#pragma unroll
    for (int r = 0; r < 4; ++r) { ps[r] = acc[r] * as_; pd[r] = acc[r] * ad_; }
#pragma unroll
    for (int r = 0; r < 4; ++r)
#pragma unroll
        for (int m = 1; m < 16; m <<= 1) {
            ps[r] += __shfl_xor(ps[r], m);
            pd[r] += __shfl_xor(pd[r], m);
        }
    if (coll == 0) {
#pragma unroll
        for (int r = 0; r < 4; ++r) {
            int row = hi * 4 + r;
            pls[0][g][row] = ps[r];
            pls[1][g][row] = pd[r];
        }
    }
#pragma unroll
    for (int r = 0; r < 4; ++r) {
        int row = hi * 4 + r;
        int col = (g * 16 + coll) ^ ((row & 3) << 4);
        hs2[row * 64 + col] = f2bf(acc[r]);
    }
    __syncthreads();
    if (t < 128) {
        int row = t >> 3;
        int chS = (t & 7) ^ ((row & 3) << 1);
        *(uint4*)(h2b + (size_t)(n0 + row) * C + (t & 7) * 8) =
            *(const uint4*)(hs2 + row * 64 + chS * 8);
    }
    if (t < 16) {
        a_src2[n0 + t] = pls[0][0][t] + pls[0][1][t] + pls[0][2][t] + pls[0][3][t];
        a_dst2[n0 + t] = pls[1][0][t] + pls[1][1][t] + pls[1][2][t] + pls[1][3][t];
    }
}

// ---------- layer 2 aggregation + classifier head: ONE WAVE PER NODE, bf16 gather ----------
__global__ void k_agg2(const int* __restrict__ rowstart, const int* __restrict__ deg,
                       const int2* __restrict__ csr,
                       const float* __restrict__ a_src2, const float* __restrict__ a_dst2,
                       const float* __restrict__ scal, const unsigned short* __restrict__ h2b,
                       const float* __restrict__ b2, const float* __restrict__ Wfc,
                       const float* __restrict__ bfc, float* __restrict__ d_out, int N) {
    __shared__ float wlds[4][64];
    int wid = threadIdx.x >> 6, lane = threadIdx.x & 63;
    int n = blockIdx.x * 4 + wid;
    int eg = lane >> 4, li = lane & 15;
    int rs = rowstart[n], cnt = deg[n];
    float adv = a_dst2[n];
    float w2  = scal[2];
    const uint2* h2v = (const uint2*)h2b;

    float M = -INFINITY, den = 0.0f;
    float4 acc = make_float4(0.f, 0.f, 0.f, 0.f);

    for (int base = 0; base < cnt; base += 64) {
        int j = base + lane;
        int sj = 0; float al = -INFINITY;
        if (j < cnt) {
            int2 cv = csr[rs + j];
            sj = cv.x;
            al = a_src2[sj] + adv + __int_as_float(cv.y) * w2;
            al = al > 0.0f ? al : NEG_SLOPE * al;
        }
        float cm = wredmax(al); cm = __shfl(cm, 0);
        float newM = fmaxf(M, cm);
        float sc = __expf(M - newM);
        den *= sc;
        acc.x *= sc; acc.y *= sc; acc.z *= sc; acc.w *= sc;
        M = newM;
        float w = __expf(al - M);
        den += w;
        wlds[wid][lane] = w;
        int m = min(64, cnt - base);
#pragma unroll 4
        for (int jj = 0; jj < m; jj += 4) {
            int idx = jj + eg;
            float ww = wlds[wid][idx];
            int   s  = __shfl(sj, idx);
            uint2 hv = h2v[(size_t)s * 16 + li];
            acc.x += __uint_as_float(hv.x << 16)         * ww;
            acc.y += __uint_as_float(hv.x & 0xffff0000u) * ww;
            acc.z += __uint_as_float(hv.y << 16)         * ww;
            acc.w += __uint_as_float(hv.y & 0xffff0000u) * ww;
        }
    }
#pragma unroll
    for (int off = 32; off >= 16; off >>= 1) {
        acc.x += __shfl_down(acc.x, off);
        acc.y += __shfl_down(acc.y, off);
        acc.z += __shfl_down(acc.z, off);
        acc.w += __shfl_down(acc.w, off);
    }
    float dt = wredsum(den); dt = __shfl(dt, 0);
    float inv = 1.0f / (dt + EPSF);
    float4 b4 = ((const float4*)b2)[li];
    float4 v;
    v.x = acc.x * inv + b4.x;
    v.y = acc.y * inv + b4.y;
    v.z = acc.z * inv + b4.z;
    v.w = acc.w * inv + b4.w;
    v.x = v.x > 0.f ? v.x : expm1f(v.x);
    v.y = v.y > 0.f ? v.y : expm1f(v.y);
    v.z = v.z > 0.f ? v.z : expm1f(v.z);
    v.w = v.w > 0.f ? v.w : expm1f(v.w);
    if (lane < 16)
        ((float4*)(d_out + (size_t)2 * N + (size_t)n * C))[li] = v;   // emb
    const float4* wfc4 = (const float4*)Wfc;
    float4 A = wfc4[li * 2], B = wfc4[li * 2 + 1];
    float p0 = v.x * A.x + v.y * A.z + v.z * B.x + v.w * B.z;
    float p1 = v.x * A.y + v.y * A.w + v.z * B.y + v.w * B.w;
#pragma unroll
    for (int off = 8; off; off >>= 1) {
        p0 += __shfl_down(p0, off);
        p1 += __shfl_down(p1, off);
    }
    if (lane == 0) {
        p0 += bfc[0]; p1 += bfc[1];
        float mm = fmaxf(p0, p1);
        float lse = mm + logf(__expf(p0 - mm) + __expf(p1 - mm));
        d_out[(size_t)n * 2]     = p0 - lse;
        d_out[(size_t)n * 2 + 1] = p1 - lse;
    }
}

extern "C" void kernel_launch(void* const* d_in, const int* in_sizes, int n_in,
                              void* d_out, int out_size, void* d_ws, size_t ws_size,
                              hipStream_t stream) {
    const float* x     = (const float*)d_in[0];
    const int*   ei    = (const int*)  d_in[1];
    const float* eattr = (const float*)d_in[2];
    const float* W1    = (const float*)d_in[3];
    const float* as1   = (const float*)d_in[4];
    const float* ad1   = (const float*)d_in[5];
    const float* We1   = (const float*)d_in[6];
    const float* ae1   = (const float*)d_in[7];
    const float* b1    = (const float*)d_in[8];
    const float* W2    = (const float*)d_in[9];
    const float* as2   = (const float*)d_in[10];
    const float* ad2   = (const float*)d_in[11];
    const float* We2   = (const float*)d_in[12];
    const float* ae2   = (const float*)d_in[13];
    const float* b2    = (const float*)d_in[14];
    const float* Wfc   = (const float*)d_in[15];
    const float* bfc   = (const float*)d_in[16];

    const int N    = in_sizes[0] / FIN;   // 50000
    const int E    = in_sizes[2];         // 800000
    const int Etot = E + N;

    char* wsb = (char*)d_ws;
    size_t off = 0;
    auto alloc = [&](size_t elems) {
        off = (off + 15) & ~(size_t)15;   // 16B align
        void* p = wsb + off; off += elems * 4; return p;
    };

    // ---- zero-initialized region (front) ----
    int*   deg    = (int*)  alloc(N);
    int*   cursor = (int*)  alloc(N);
    float* scal   = (float*)alloc(8);
    size_t zero_bytes = (off + 15) & ~(size_t)15;
    // ---- rest ----
    int*   rowstart = (int*)  alloc(N);
    int*   bsums    = (int*)  alloc(256);
    int2*  csr      = (int2*) alloc((size_t)Etot * 2);
    unsigned int*   xb     = (unsigned int*)  alloc((size_t)N * 64);    // bf16 x, packed
    unsigned short* xaggb  = (unsigned short*)alloc((size_t)N * 256);   // [N][4][128] bf16 (N*1024 B)
    unsigned short* h2b    = (unsigned short*)alloc((size_t)N * 32);    // [N][64] bf16
    unsigned short* W1f    = (unsigned short*)alloc(16384);             // 32768 bf16
    unsigned short* W2f    = (unsigned short*)alloc(8192);              // 16384 bf16
    float* vsd     = (float*)alloc(1024);                               // [2][4][128]
    float* a_src1  = (float*)alloc((size_t)N * H1);
    float* a_dst1  = (float*)alloc((size_t)N * H1);
    float* a_src2  = (float*)alloc(N);
    float* a_dst2  = (float*)alloc(N);

    hipMemsetAsync(d_ws, 0, zero_bytes, stream);

    int ge = (Etot + 255) / 256;
    int nb = (N + 255) / 256;
    k_hist_ea<<<ge, 256, 0, stream>>>(ei, eattr, deg, scal, E, Etot);
    k_prep<<<1, 256, 0, stream>>>(We1, ae1, We2, ae2, scal, 1.0f / (float)E);
    k_prepvec<<<4, 256, 0, stream>>>(W1, as1, ad1, vsd);
    k_convw<<<128, 256, 0, stream>>>(W1, W2, W1f, W2f);
    k_scan1<<<nb, 256, 0, stream>>>(deg, rowstart, bsums, N);
    k_scan2<<<1, 256, 0, stream>>>(bsums, nb);
    k_scan3<<<nb, 256, 0, stream>>>(rowstart, bsums, N);
    k_scatter<<<ge, 256, 0, stream>>>(ei, eattr, scal, rowstart, cursor, csr, E, Etot);

    k_convx<<<N / 4, 256, 0, stream>>>(x, vsd, xb, a_src1, a_dst1);
    k_agg1x<<<N / 4, 256, 0, stream>>>(rowstart, deg, csr, a_src1, a_dst1, scal,
                                       (const uint2*)xb, (uint2*)xaggb);
    k_fused12<<<N / 16, 256, 0, stream>>>(xaggb, W1f, b1, W2f, as2, ad2,
                                          h2b, a_src2, a_dst2);
    k_agg2<<<N / 4, 256, 0, stream>>>(rowstart, deg, csr, a_src2, a_dst2, scal, h2b,
                                      b2, Wfc, bfc, (float*)d_out, N);
}

// Round 12
// 373.626 us; speedup vs baseline: 1.4463x; 1.4463x over previous
//
#include <hip/hip_runtime.h>
#include <math.h>

#define NEG_SLOPE 0.2f
#define EPSF 1e-16f

constexpr int FIN = 128;
constexpr int H1  = 4;
constexpr int C   = 64;
constexpr int HC  = 256;   // H1 * C

typedef __attribute__((ext_vector_type(8))) short bf16x8;
typedef __attribute__((ext_vector_type(4))) float f32x4;

__device__ inline float wredsum(float v) {
#pragma unroll
    for (int off = 32; off; off >>= 1) v += __shfl_down(v, off);
    return v;
}
__device__ inline float wredmax(float v) {
#pragma unroll
    for (int off = 32; off; off >>= 1) v = fmaxf(v, __shfl_down(v, off));
    return v;
}
__device__ inline float4 wredmax4(float4 v) {
#pragma unroll
    for (int off = 32; off; off >>= 1) {
        v.x = fmaxf(v.x, __shfl_down(v.x, off));
        v.y = fmaxf(v.y, __shfl_down(v.y, off));
        v.z = fmaxf(v.z, __shfl_down(v.z, off));
        v.w = fmaxf(v.w, __shfl_down(v.w, off));
    }
    return v;
}
__device__ inline float4 wredsum4(float4 v) {
#pragma unroll
    for (int off = 32; off; off >>= 1) {
        v.x += __shfl_down(v.x, off);
        v.y += __shfl_down(v.y, off);
        v.z += __shfl_down(v.z, off);
        v.w += __shfl_down(v.w, off);
    }
    return v;
}
__device__ inline float4 bcast4(float4 v) {
    v.x = __shfl(v.x, 0); v.y = __shfl(v.y, 0);
    v.z = __shfl(v.z, 0); v.w = __shfl(v.w, 0);
    return v;
}
__device__ inline float comp4(float4 v, int i) {
    return i == 0 ? v.x : (i == 1 ? v.y : (i == 2 ? v.z : v.w));
}
__device__ inline unsigned short f2bf(float f) {   // RNE
    unsigned u = __float_as_uint(f);
    return (unsigned short)((u + 0x7fffu + ((u >> 16) & 1u)) >> 16);
}

// ---------- merged histogram + edge_attr sum ----------
__global__ void k_hist_ea(const int* __restrict__ ei, const float* __restrict__ eattr,
                          int* __restrict__ deg, float* __restrict__ scal, int E, int Etot) {
    int e = blockIdx.x * blockDim.x + threadIdx.x;
    float v = 0.0f;
    if (e < Etot) {
        int d = (e < E) ? ei[E + e] : e - E;
        atomicAdd(&deg[d], 1);
        if (e < E) v = eattr[e];
    }
    v = wredsum(v);
    __shared__ float sm[4];
    if ((threadIdx.x & 63) == 0) sm[threadIdx.x >> 6] = v;
    __syncthreads();
    if (threadIdx.x == 0) atomicAdd(scal, sm[0] + sm[1] + sm[2] + sm[3]);
}

// scal[1]=ea_mean, scal[2]=we2dot, scal[4..7]=we1dot[h]
__global__ void k_prep(const float* __restrict__ We1, const float* __restrict__ ae1,
                       const float* __restrict__ We2, const float* __restrict__ ae2,
                       float* __restrict__ scal, float inv_E) {
    int t = threadIdx.x;
    float p = We1[t] * ae1[t];
    p = wredsum(p);
    if ((t & 63) == 0) scal[4 + (t >> 6)] = p;
    if (t < 64) {
        float q = We2[t] * ae2[t];
        q = wredsum(q);
        if (t == 0) scal[2] = q;
    }
    if (t == 0) scal[1] = scal[0] * inv_E;
}

// ---------- vsd[which][h][k] = sum_c W1[k, h*64+c] * att[h][c] ----------
__global__ void k_prepvec(const float* __restrict__ W1, const float* __restrict__ as1,
                          const float* __restrict__ ad1, float* __restrict__ vsd) {
    int idx = blockIdx.x * 256 + threadIdx.x;   // 0..1023
    int which = idx >> 9, h = (idx >> 7) & 3, k = idx & 127;
    const float* att = which ? ad1 : as1;
    float s = 0.0f;
#pragma unroll 8
    for (int c = 0; c < 64; ++c) s += W1[k * HC + h * 64 + c] * att[h * 64 + c];
    vsd[idx] = s;
}

// ---------- convert W1/W2 to bf16 MFMA fragment order ----------
__global__ void k_convw(const float* __restrict__ W1, const float* __restrict__ W2,
                        unsigned short* __restrict__ W1f, unsigned short* __restrict__ W2f) {
    int idx = blockIdx.x * 256 + threadIdx.x;   // 32768 total
    {
        int j = idx & 7, l = (idx >> 3) & 63, t = (idx >> 9) & 3, q = idx >> 11;
        int k = t * 32 + (l >> 4) * 8 + j;
        int n = 16 * q + (l & 15);
        W1f[idx] = f2bf(W1[k * HC + n]);
    }
    if (idx < 16384) {
        int j = idx & 7, l = (idx >> 3) & 63, t = (idx >> 9) & 7, g = idx >> 12;
        int k = t * 32 + (l >> 4) * 8 + j;
        int c = 16 * g + (l & 15);
        W2f[idx] = f2bf(W2[k * C + c]);
    }
}

// ---------- CSR scans + scatter ----------
__global__ void k_scan1(const int* __restrict__ deg, int* __restrict__ rowstart,
                        int* __restrict__ bsums, int N) {
    __shared__ int sm[256];
    int i = blockIdx.x * 256 + threadIdx.x;
    int v = (i < N) ? deg[i] : 0;
    sm[threadIdx.x] = v;
    __syncthreads();
    for (int off = 1; off < 256; off <<= 1) {
        int t = (threadIdx.x >= off) ? sm[threadIdx.x - off] : 0;
        __syncthreads();
        sm[threadIdx.x] += t;
        __syncthreads();
    }
    if (i < N) rowstart[i] = sm[threadIdx.x] - v;   // exclusive
    if (threadIdx.x == 255) bsums[blockIdx.x] = sm[255];
}

__global__ void k_scan2(int* __restrict__ bsums, int nb) {
    __shared__ int sm[256];
    int v = (threadIdx.x < nb) ? bsums[threadIdx.x] : 0;
    sm[threadIdx.x] = v;
    __syncthreads();
    for (int off = 1; off < 256; off <<= 1) {
        int t = (threadIdx.x >= off) ? sm[threadIdx.x - off] : 0;
        __syncthreads();
        sm[threadIdx.x] += t;
        __syncthreads();
    }
    if (threadIdx.x < nb) bsums[threadIdx.x] = sm[threadIdx.x] - v;   // exclusive
}

__global__ void k_scan3(int* __restrict__ rowstart, const int* __restrict__ bsums, int N) {
    int i = blockIdx.x * 256 + threadIdx.x;
    if (i < N) rowstart[i] += bsums[blockIdx.x];
}

__global__ void k_scatter(const int* __restrict__ ei, const float* __restrict__ eattr,
                          const float* __restrict__ scal, const int* __restrict__ rowstart,
                          int* __restrict__ cursor, int2* __restrict__ csr, int E, int Etot) {
    int e = blockIdx.x * blockDim.x + threadIdx.x;
    if (e >= Etot) return;
    int s, d; float ea;
    if (e < E) { s = ei[e]; d = ei[E + e]; ea = eattr[e]; }
    else       { s = e - E; d = s;          ea = scal[1]; }
    int pos = atomicAdd(&cursor[d], 1);
    csr[rowstart[d] + pos] = make_int2(s, __float_as_int(ea));
}

// ---------- convert x -> bf16, compute a_src1/a_dst1 via precomputed vectors ----------
// one wave per node; lane l covers channels 2l, 2l+1
__global__ void k_convx(const float* __restrict__ x, const float* __restrict__ vsd,
                        unsigned int* __restrict__ xb,
                        float* __restrict__ a_src, float* __restrict__ a_dst) {
    int wid = threadIdx.x >> 6, l = threadIdx.x & 63;
    int n = blockIdx.x * 4 + wid;
    float2 xv = ((const float2*)x)[(size_t)n * 64 + l];
    const float2* vs2 = (const float2*)vsd;
    float4 A, B;
    {
        float2 a0 = vs2[l],        a1 = vs2[64 + l];
        float2 a2 = vs2[128 + l],  a3 = vs2[192 + l];
        A.x = xv.x * a0.x + xv.y * a0.y;
        A.y = xv.x * a1.x + xv.y * a1.y;
        A.z = xv.x * a2.x + xv.y * a2.y;
        A.w = xv.x * a3.x + xv.y * a3.y;
        float2 b0 = vs2[256 + l],  b1 = vs2[320 + l];
        float2 b2 = vs2[384 + l],  b3 = vs2[448 + l];
        B.x = xv.x * b0.x + xv.y * b0.y;
        B.y = xv.x * b1.x + xv.y * b1.y;
        B.z = xv.x * b2.x + xv.y * b2.y;
        B.w = xv.x * b3.x + xv.y * b3.y;
    }
    A = wredsum4(A);
    B = wredsum4(B);
    if (l == 0) {
        ((float4*)a_src)[n] = A;
        ((float4*)a_dst)[n] = B;
    }
    xb[(size_t)n * 64 + l] = f2bf(xv.x) | ((unsigned)f2bf(xv.y) << 16);
}

// ---------- layer 1 aggregation in x-space: per-head xagg, bf16 gather 256 B/edge ----------
// one wave per node; half = lane>>5 handles edges jj+half; lane covers channels 4hl..4hl+3
__global__ void k_agg1x(const int* __restrict__ rowstart, const int* __restrict__ deg,
                        const int2* __restrict__ csr,
                        const float* __restrict__ a_src, const float* __restrict__ a_dst,
                        const float* __restrict__ scal, const uint2* __restrict__ xb2,
                        uint2* __restrict__ xaggb2) {
    __shared__ float4 wlds[4][64];
    int wid = threadIdx.x >> 6, lane = threadIdx.x & 63;
    int n = blockIdx.x * 4 + wid;
    int half = lane >> 5, hl = lane & 31;
    int rs = rowstart[n], cnt = deg[n];
    const float4 adv = ((const float4*)a_dst)[n];
    const float4 wh  = *((const float4*)(scal + 4));

    float4 M = make_float4(-INFINITY, -INFINITY, -INFINITY, -INFINITY);
    float4 den = make_float4(0.f, 0.f, 0.f, 0.f);
    float acc[4][4];   // ALL accesses compile-time indexed (rule #20)
#pragma unroll
    for (int h = 0; h < 4; ++h)
#pragma unroll
        for (int c = 0; c < 4; ++c) acc[h][c] = 0.0f;

    for (int base = 0; base < cnt; base += 64) {
        int j = base + lane;
        int sj = 0;
        float4 al = make_float4(-INFINITY, -INFINITY, -INFINITY, -INFINITY);
        if (j < cnt) {
            int2 cv = csr[rs + j];
            sj = cv.x;
            float ea = __int_as_float(cv.y);
            float4 as4 = ((const float4*)a_src)[sj];
            al.x = as4.x + adv.x + ea * wh.x;
            al.y = as4.y + adv.y + ea * wh.y;
            al.z = as4.z + adv.z + ea * wh.z;
            al.w = as4.w + adv.w + ea * wh.w;
            al.x = al.x > 0.f ? al.x : NEG_SLOPE * al.x;
            al.y = al.y > 0.f ? al.y : NEG_SLOPE * al.y;
            al.z = al.z > 0.f ? al.z : NEG_SLOPE * al.z;
            al.w = al.w > 0.f ? al.w : NEG_SLOPE * al.w;
        }
        float4 cm = bcast4(wredmax4(al));
        float4 newM = make_float4(fmaxf(M.x, cm.x), fmaxf(M.y, cm.y),
                                  fmaxf(M.z, cm.z), fmaxf(M.w, cm.w));
        float4 sc = make_float4(__expf(M.x - newM.x), __expf(M.y - newM.y),
                                __expf(M.z - newM.z), __expf(M.w - newM.w));
        den.x *= sc.x; den.y *= sc.y; den.z *= sc.z; den.w *= sc.w;
#pragma unroll
        for (int h = 0; h < 4; ++h) {
            float s = comp4(sc, h);
#pragma unroll
            for (int c = 0; c < 4; ++c) acc[h][c] *= s;
        }
        M = newM;
        float4 w4 = make_float4(__expf(al.x - M.x), __expf(al.y - M.y),
                                __expf(al.z - M.z), __expf(al.w - M.w));
        den.x += w4.x; den.y += w4.y; den.z += w4.z; den.w += w4.w;
        wlds[wid][lane] = w4;
        int m = min(64, cnt - base);
        for (int jj = 0; jj < m; jj += 2) {
            int idx = jj + half;                 // idx <= 63; padded entries have w=0
            float4 we = wlds[wid][idx];
            int s = __shfl(sj, idx);
            uint2 v = xb2[(size_t)s * 32 + hl];
            float c0 = __uint_as_float(v.x << 16);
            float c1 = __uint_as_float(v.x & 0xffff0000u);
            float c2 = __uint_as_float(v.y << 16);
            float c3 = __uint_as_float(v.y & 0xffff0000u);
            acc[0][0] += c0 * we.x; acc[0][1] += c1 * we.x;
            acc[0][2] += c2 * we.x; acc[0][3] += c3 * we.x;
            acc[1][0] += c0 * we.y; acc[1][1] += c1 * we.y;
            acc[1][2] += c2 * we.y; acc[1][3] += c3 * we.y;
            acc[2][0] += c0 * we.z; acc[2][1] += c1 * we.z;
            acc[2][2] += c2 * we.z; acc[2][3] += c3 * we.z;
            acc[3][0] += c0 * we.w; acc[3][1] += c1 * we.w;
            acc[3][2] += c2 * we.w; acc[3][3] += c3 * we.w;
        }
    }
    float4 dt = bcast4(wredsum4(den));
    float4 inv = make_float4(1.0f / (dt.x + EPSF), 1.0f / (dt.y + EPSF),
                             1.0f / (dt.z + EPSF), 1.0f / (dt.w + EPSF));
    // combine edge-halves: lanes l and l^32 both end with the full sum
#pragma unroll
    for (int h = 0; h < 4; ++h)
#pragma unroll
        for (int c = 0; c < 4; ++c) acc[h][c] += __shfl_xor(acc[h][c], 32);
    // lane outputs heads 2*half, 2*half+1 — select with STATIC dst indices (no
    // runtime array index: that demotes acc to LDS scratch; cost = 3x, round 11)
    float sel[2][4];
#pragma unroll
    for (int h = 0; h < 4; ++h) {
        float ivh = comp4(inv, h);
        bool mine = ((h >> 1) == half);
#pragma unroll
        for (int c = 0; c < 4; ++c) {
            float v = acc[h][c] * ivh;
            if (mine) sel[h & 1][c] = v;
        }
    }
    uint2 o0, o1;
    o0.x = f2bf(sel[0][0]) | ((unsigned)f2bf(sel[0][1]) << 16);
    o0.y = f2bf(sel[0][2]) | ((unsigned)f2bf(sel[0][3]) << 16);
    o1.x = f2bf(sel[1][0]) | ((unsigned)f2bf(sel[1][1]) << 16);
    o1.y = f2bf(sel[1][2]) | ((unsigned)f2bf(sel[1][3]) << 16);
    int h0 = half * 2;
    xaggb2[((size_t)n * 4 + h0) * 32 + hl]     = o0;
    xaggb2[((size_t)n * 4 + h0 + 1) * 32 + hl] = o1;
}

// ---------- fused layer-1 GEMM + ELU + layer-2 GEMM (MFMA), out1 never leaves LDS ----------
// 16 nodes/block, 4 waves. Phase1: wave g = head g. Phase2: wave g = col-tile g.
__global__ void k_fused12(const unsigned short* __restrict__ xaggb,
                          const unsigned short* __restrict__ W1f,
                          const float* __restrict__ b1,
                          const unsigned short* __restrict__ W2f,
                          const float* __restrict__ attsrc, const float* __restrict__ attdst,
                          unsigned short* __restrict__ h2b,
                          float* __restrict__ a_src2, float* __restrict__ a_dst2) {
    __shared__ unsigned short ols[16 * 256];   // 8 KB out1 tile, swizzled
    __shared__ unsigned short hs2[16 * 64];    // 2 KB h2 repack
    __shared__ float pls[2][4][16];
    int t = threadIdx.x;
    int n0 = blockIdx.x * 16;
    int g = t >> 6, l = t & 63;
    int coll = l & 15, hi = l >> 4;
    // phase 1: out1 = ELU(xagg[:,g] @ W1[:,64g..] + b1)
    const bf16x8* af = (const bf16x8*)xaggb;
    size_t abase = ((size_t)(n0 + coll) * 4 + g) * 16;
    bf16x8 a[4];
#pragma unroll
    for (int k = 0; k < 4; ++k) a[k] = af[abase + k * 4 + hi];
    const bf16x8* wf1 = (const bf16x8*)W1f;
    f32x4 acc1[4];
#pragma unroll
    for (int ct = 0; ct < 4; ++ct) {
        f32x4 c = {0.f, 0.f, 0.f, 0.f};
#pragma unroll
        for (int k = 0; k < 4; ++k) {
            bf16x8 b = wf1[((g * 4 + ct) * 4 + k) * 64 + l];
            c = __builtin_amdgcn_mfma_f32_16x16x32_bf16(a[k], b, c, 0, 0, 0);
        }
        acc1[ct] = c;
    }
#pragma unroll
    for (int ct = 0; ct < 4; ++ct)
#pragma unroll
        for (int r = 0; r < 4; ++r) {
            int row = hi * 4 + r;
            int col = g * 64 + ct * 16 + coll;
            float v = acc1[ct][r] + b1[col];
            v = v > 0.f ? v : expm1f(v);
            ols[row * 256 + (((col >> 3) ^ (row & 7)) << 3) + (col & 7)] = f2bf(v);
        }
    __syncthreads();
    // phase 2: h2 = out1 @ W2 (K=256, 8 k-steps); wave g = cols 16g..16g+15
    const bf16x8* wf2 = (const bf16x8*)W2f;
    f32x4 acc = {0.f, 0.f, 0.f, 0.f};
#pragma unroll
    for (int k = 0; k < 8; ++k) {
        int ch = (k * 4 + hi) ^ (coll & 7);
        bf16x8 av = *(const bf16x8*)((const char*)ols + coll * 512 + ch * 16);
        bf16x8 bv = wf2[(g * 8 + k) * 64 + l];
        acc = __builtin_amdgcn_mfma_f32_16x16x32_bf16(av, bv, acc, 0, 0, 0);
    }
    float as_ = attsrc[g * 16 + coll];
    float ad_ = attdst[g * 16 + coll];
    float ps[4], pd[4];
#pragma unroll
    for (int r = 0; r < 4; ++r) { ps[r] = acc[r] * as_; pd[r] = acc[r] * ad_; }
#pragma unroll
    for (int r = 0; r < 4; ++r)
#pragma unroll
        for (int m = 1; m < 16; m <<= 1) {
            ps[r] += __shfl_xor(ps[r], m);
            pd[r] += __shfl_xor(pd[r], m);
        }
    if (coll == 0) {
#pragma unroll
        for (int r = 0; r < 4; ++r) {
            int row = hi * 4 + r;
            pls[0][g][row] = ps[r];
            pls[1][g][row] = pd[r];
        }
    }
#pragma unroll
    for (int r = 0; r < 4; ++r) {
        int row = hi * 4 + r;
        int col = (g * 16 + coll) ^ ((row & 3) << 4);
        hs2[row * 64 + col] = f2bf(acc[r]);
    }
    __syncthreads();
    if (t < 128) {
        int row = t >> 3;
        int chS = (t & 7) ^ ((row & 3) << 1);
        *(uint4*)(h2b + (size_t)(n0 + row) * C + (t & 7) * 8) =
            *(const uint4*)(hs2 + row * 64 + chS * 8);
    }
    if (t < 16) {
        a_src2[n0 + t] = pls[0][0][t] + pls[0][1][t] + pls[0][2][t] + pls[0][3][t];
        a_dst2[n0 + t] = pls[1][0][t] + pls[1][1][t] + pls[1][2][t] + pls[1][3][t];
    }
}

// ---------- layer 2 aggregation + classifier head: ONE WAVE PER NODE, bf16 gather ----------
__global__ void k_agg2(const int* __restrict__ rowstart, const int* __restrict__ deg,
                       const int2* __restrict__ csr,
                       const float* __restrict__ a_src2, const float* __restrict__ a_dst2,
                       const float* __restrict__ scal, const unsigned short* __restrict__ h2b,
                       const float* __restrict__ b2, const float* __restrict__ Wfc,
                       const float* __restrict__ bfc, float* __restrict__ d_out, int N) {
    __shared__ float wlds[4][64];
    int wid = threadIdx.x >> 6, lane = threadIdx.x & 63;
    int n = blockIdx.x * 4 + wid;
    int eg = lane >> 4, li = lane & 15;
    int rs = rowstart[n], cnt = deg[n];
    float adv = a_dst2[n];
    float w2  = scal[2];
    const uint2* h2v = (const uint2*)h2b;

    float M = -INFINITY, den = 0.0f;
    float4 acc = make_float4(0.f, 0.f, 0.f, 0.f);

    for (int base = 0; base < cnt; base += 64) {
        int j = base + lane;
        int sj = 0; float al = -INFINITY;
        if (j < cnt) {
            int2 cv = csr[rs + j];
            sj = cv.x;
            al = a_src2[sj] + adv + __int_as_float(cv.y) * w2;
            al = al > 0.0f ? al : NEG_SLOPE * al;
        }
        float cm = wredmax(al); cm = __shfl(cm, 0);
        float newM = fmaxf(M, cm);
        float sc = __expf(M - newM);
        den *= sc;
        acc.x *= sc; acc.y *= sc; acc.z *= sc; acc.w *= sc;
        M = newM;
        float w = __expf(al - M);
        den += w;
        wlds[wid][lane] = w;
        int m = min(64, cnt - base);
#pragma unroll 4
        for (int jj = 0; jj < m; jj += 4) {
            int idx = jj + eg;
            float ww = wlds[wid][idx];
            int   s  = __shfl(sj, idx);
            uint2 hv = h2v[(size_t)s * 16 + li];
            acc.x += __uint_as_float(hv.x << 16)         * ww;
            acc.y += __uint_as_float(hv.x & 0xffff0000u) * ww;
            acc.z += __uint_as_float(hv.y << 16)         * ww;
            acc.w += __uint_as_float(hv.y & 0xffff0000u) * ww;
        }
    }
#pragma unroll
    for (int off = 32; off >= 16; off >>= 1) {
        acc.x += __shfl_down(acc.x, off);
        acc.y += __shfl_down(acc.y, off);
        acc.z += __shfl_down(acc.z, off);
        acc.w += __shfl_down(acc.w, off);
    }
    float dt = wredsum(den); dt = __shfl(dt, 0);
    float inv = 1.0f / (dt + EPSF);
    float4 b4 = ((const float4*)b2)[li];
    float4 v;
    v.x = acc.x * inv + b4.x;
    v.y = acc.y * inv + b4.y;
    v.z = acc.z * inv + b4.z;
    v.w = acc.w * inv + b4.w;
    v.x = v.x > 0.f ? v.x : expm1f(v.x);
    v.y = v.y > 0.f ? v.y : expm1f(v.y);
    v.z = v.z > 0.f ? v.z : expm1f(v.z);
    v.w = v.w > 0.f ? v.w : expm1f(v.w);
    if (lane < 16)
        ((float4*)(d_out + (size_t)2 * N + (size_t)n * C))[li] = v;   // emb
    const float4* wfc4 = (const float4*)Wfc;
    float4 A = wfc4[li * 2], B = wfc4[li * 2 + 1];
    float p0 = v.x * A.x + v.y * A.z + v.z * B.x + v.w * B.z;
    float p1 = v.x * A.y + v.y * A.w + v.z * B.y + v.w * B.w;
#pragma unroll
    for (int off = 8; off; off >>= 1) {
        p0 += __shfl_down(p0, off);
        p1 += __shfl_down(p1, off);
    }
    if (lane == 0) {
        p0 += bfc[0]; p1 += bfc[1];
        float mm = fmaxf(p0, p1);
        float lse = mm + logf(__expf(p0 - mm) + __expf(p1 - mm));
        d_out[(size_t)n * 2]     = p0 - lse;
        d_out[(size_t)n * 2 + 1] = p1 - lse;
    }
}

extern "C" void kernel_launch(void* const* d_in, const int* in_sizes, int n_in,
                              void* d_out, int out_size, void* d_ws, size_t ws_size,
                              hipStream_t stream) {
    const float* x     = (const float*)d_in[0];
    const int*   ei    = (const int*)  d_in[1];
    const float* eattr = (const float*)d_in[2];
    const float* W1    = (const float*)d_in[3];
    const float* as1   = (const float*)d_in[4];
    const float* ad1   = (const float*)d_in[5];
    const float* We1   = (const float*)d_in[6];
    const float* ae1   = (const float*)d_in[7];
    const float* b1    = (const float*)d_in[8];
    const float* W2    = (const float*)d_in[9];
    const float* as2   = (const float*)d_in[10];
    const float* ad2   = (const float*)d_in[11];
    const float* We2   = (const float*)d_in[12];
    const float* ae2   = (const float*)d_in[13];
    const float* b2    = (const float*)d_in[14];
    const float* Wfc   = (const float*)d_in[15];
    const float* bfc   = (const float*)d_in[16];

    const int N    = in_sizes[0] / FIN;   // 50000
    const int E    = in_sizes[2];         // 800000
    const int Etot = E + N;

    char* wsb = (char*)d_ws;
    size_t off = 0;
    auto alloc = [&](size_t elems) {
        off = (off + 15) & ~(size_t)15;   // 16B align
        void* p = wsb + off; off += elems * 4; return p;
    };

    // ---- zero-initialized region (front) ----
    int*   deg    = (int*)  alloc(N);
    int*   cursor = (int*)  alloc(N);
    float* scal   = (float*)alloc(8);
    size_t zero_bytes = (off + 15) & ~(size_t)15;
    // ---- rest ----
    int*   rowstart = (int*)  alloc(N);
    int*   bsums    = (int*)  alloc(256);
    int2*  csr      = (int2*) alloc((size_t)Etot * 2);
    unsigned int*   xb     = (unsigned int*)  alloc((size_t)N * 64);    // bf16 x, packed
    unsigned short* xaggb  = (unsigned short*)alloc((size_t)N * 256);   // [N][4][128] bf16 (N*1024 B)
    unsigned short* h2b    = (unsigned short*)alloc((size_t)N * 32);    // [N][64] bf16
    unsigned short* W1f    = (unsigned short*)alloc(16384);             // 32768 bf16
    unsigned short* W2f    = (unsigned short*)alloc(8192);              // 16384 bf16
    float* vsd     = (float*)alloc(1024);                               // [2][4][128]
    float* a_src1  = (float*)alloc((size_t)N * H1);
    float* a_dst1  = (float*)alloc((size_t)N * H1);
    float* a_src2  = (float*)alloc(N);
    float* a_dst2  = (float*)alloc(N);

    hipMemsetAsync(d_ws, 0, zero_bytes, stream);

    int ge = (Etot + 255) / 256;
    int nb = (N + 255) / 256;
    k_hist_ea<<<ge, 256, 0, stream>>>(ei, eattr, deg, scal, E, Etot);
    k_prep<<<1, 256, 0, stream>>>(We1, ae1, We2, ae2, scal, 1.0f / (float)E);
    k_prepvec<<<4, 256, 0, stream>>>(W1, as1, ad1, vsd);
    k_convw<<<128, 256, 0, stream>>>(W1, W2, W1f, W2f);
    k_scan1<<<nb, 256, 0, stream>>>(deg, rowstart, bsums, N);
    k_scan2<<<1, 256, 0, stream>>>(bsums, nb);
    k_scan3<<<nb, 256, 0, stream>>>(rowstart, bsums, N);
    k_scatter<<<ge, 256, 0, stream>>>(ei, eattr, scal, rowstart, cursor, csr, E, Etot);

    k_convx<<<N / 4, 256, 0, stream>>>(x, vsd, xb, a_src1, a_dst1);
    k_agg1x<<<N / 4, 256, 0, stream>>>(rowstart, deg, csr, a_src1, a_dst1, scal,
                                       (const uint2*)xb, (uint2*)xaggb);
    k_fused12<<<N / 16, 256, 0, stream>>>(xaggb, W1f, b1, W2f, as2, ad2,
                                          h2b, a_src2, a_dst2);
    k_agg2<<<N / 4, 256, 0, stream>>>(rowstart, deg, csr, a_src2, a_dst2, scal, h2b,
                                      b2, Wfc, bfc, (float*)d_out, N);
}